// Round 6
// baseline (332.522 us; speedup 1.0000x reference)
//
#include <hip/hip_runtime.h>
#include <cmath>

#define BB 16
#define PP 4096
#define QQ 1024
#define DD 256

typedef __attribute__((ext_vector_type(8))) short short8;
typedef __attribute__((ext_vector_type(4))) float floatx4;
typedef __attribute__((ext_vector_type(4))) _Float16 half4;

static __device__ inline ushort bf16_rne(float x) {
  unsigned u = __float_as_uint(x);
  unsigned r = (u + 0x7fffu + ((u >> 16) & 1u)) >> 16;
  return (ushort)r;
}
static __device__ inline float bf16f(ushort h) { return __uint_as_float(((unsigned)h) << 16); }

static __device__ inline float ftanh(float x) {
  float e = __expf(2.0f * x);
  return 1.0f - 2.0f * __builtin_amdgcn_rcpf(e + 1.0f);
}

static __device__ inline void gl16(const void* g, void* l) {
  __builtin_amdgcn_global_load_lds(
      (const __attribute__((address_space(1))) unsigned int*)g,
      (__attribute__((address_space(3))) unsigned int*)l, 16, 0, 0);
}

// ---------------------------------------------------------------------------
// kQprep: Q -> per-(b,32q-tile) 48KB blobs: [SQhi 16K | SQlo 16K | TQhi 16K].
//  SQ: row-major hi/lo, granule j of row r at slot j^(r&7).
//  TQ: transposed [d][32q] bf16-hi only, granule k at slot k^((d>>1)&3).
// ---------------------------------------------------------------------------
__global__ __launch_bounds__(256) void kQprep(
    const float* __restrict__ ques, ushort* __restrict__ qb)
{
  const int b = blockIdx.y, qt = blockIdx.x;
  __shared__ float tile[32][260];
  const int tid = threadIdx.x;
  const float* src = ques + ((size_t)b * QQ + qt * 32) * DD;
  for (int i = tid; i < 32 * 64; i += 256) {
    int r = i >> 6, c = (i & 63) << 2;
    *(float4*)&tile[r][c] = *(const float4*)(src + r * DD + c);
  }
  __syncthreads();
  ushort* blob = qb + (size_t)(b * 32 + qt) * 24576;
  {
    int r = tid >> 3;
    int j0 = (tid & 7) * 4;
#pragma unroll
    for (int jj = 0; jj < 4; ++jj) {
      int j = j0 + jj;
      ushort h8[8], l8[8];
#pragma unroll
      for (int e = 0; e < 8; ++e) {
        float x = tile[r][j * 8 + e];
        ushort h = bf16_rne(x);
        h8[e] = h; l8[e] = bf16_rne(x - bf16f(h));
      }
      int g = r * 32 + (j ^ (r & 7));
      *(uint4*)&blob[(size_t)g * 8] = *(uint4*)h8;
      *(uint4*)&blob[8192 + (size_t)g * 8] = *(uint4*)l8;
    }
  }
  {
    int d = tid;
    int s = (d >> 1) & 3;
    ushort h32[32];
#pragma unroll
    for (int r = 0; r < 32; ++r) h32[r] = bf16_rne(tile[r][d]);
#pragma unroll
    for (int k = 0; k < 4; ++k)
      *(uint4*)&blob[16384 + (size_t)d * 32 + (k ^ s) * 8] = *(uint4*)&h32[k * 8];
  }
}

// ---------------------------------------------------------------------------
// kA: flash attention, cross-iteration pipelined (round-0 structure).
// 512 thr = 8 waves x 16 p-rows; triple-buffered 48KB Q tiles (1 block/CU).
// iter t: DMA(t+1) | GEMM1(t) | GEMM2(t-1) (P in regs) | softmax(t) | Ptrans(t).
// GEMM1 accumulators split by term (hh/hl/lh): 6 independent MFMA dependency
// chains instead of 2 -> latency-bound -> throughput-bound.
// Fixed-shift softmax (C=60), l/rowmax reductions deferred to the end.
// Epilogue FUSES kB2: per-block q2c partials (weight e^{rowmax-60}).
// ---------------------------------------------------------------------------
__global__ __launch_bounds__(512, 1) void kA(
    const float* __restrict__ pass, const ushort* __restrict__ qb,
    const float* __restrict__ w_attn,
    _Float16* __restrict__ first_h, _Float16* __restrict__ tp_h,
    float* __restrict__ logit1,
    float* __restrict__ numpart, float* __restrict__ denpart)
{
  __shared__ alignas(16) char sm[147456];  // 3 x 48KB buffers

  const int b    = blockIdx.y;
  const int p0   = blockIdx.x * 128;
  const int tid  = threadIdx.x;
  const int w    = tid >> 6;
  const int lane = tid & 63;
  const int l15  = lane & 15;
  const int quad = lane >> 4;
  const int swz  = l15 & 7;

  // passage B-fragments (hi/lo), once per block
  short8 bhi[8], blo[8];
  {
    const float* prow = pass + (((size_t)b * PP + p0 + w * 16 + l15) * DD);
#pragma unroll
    for (int c = 0; c < 8; ++c) {
      const float* p8 = prow + c * 32 + quad * 8;
      float4 x0 = *(const float4*)p8;
      float4 x1 = *(const float4*)(p8 + 4);
      float xs[8] = {x0.x, x0.y, x0.z, x0.w, x1.x, x1.y, x1.z, x1.w};
#pragma unroll
      for (int j = 0; j < 8; ++j) {
        ushort h = bf16_rne(xs[j]);
        ushort lo = bf16_rne(xs[j] - bf16f(h));
        bhi[c][j] = (short)h;
        blo[c][j] = (short)lo;
      }
    }
  }

  int goff[8];
#pragma unroll
  for (int c = 0; c < 8; ++c) goff[c] = (l15 * 32 + ((4 * c + quad) ^ swz)) * 8;
  const int vtoff = l15 * 32 + ((quad ^ ((l15 >> 1) & 3)) * 8);

  const ushort* tb = qb + (size_t)b * 32 * 24576;
  const int dma_l = w * 3072 + lane * 8;   // ushort offset in blob
  const int dma_s = w * 6144 + lane * 16;  // byte offset in LDS buffer

  floatx4 accO[16];
#pragma unroll
  for (int i = 0; i < 16; ++i) accO[i] = (floatx4){0.f, 0.f, 0.f, 0.f};
  float mx = -INFINITY, ps = 0.f;
  short8 phi = {0, 0, 0, 0, 0, 0, 0, 0}, plo = {0, 0, 0, 0, 0, 0, 0, 0};

  // DMA(0) -> buf0
  {
    const ushort* gs = tb + dma_l;
    char* ld = sm + dma_s;
#pragma unroll
    for (int i = 0; i < 6; ++i) gl16(gs + i * 512, ld + i * 1024);
  }
  __syncthreads();

  for (int t = 0; t < 32; ++t) {
    const int ic = t % 3, ip = (t + 2) % 3, inx = (t + 1) % 3;
    char* cur = sm + ic * 49152;
    char* prv = sm + ip * 49152;
    if (t < 31) {
      const ushort* gs = tb + (size_t)(t + 1) * 24576 + dma_l;
      char* ld = sm + inx * 49152 + dma_s;
#pragma unroll
      for (int i = 0; i < 6; ++i) gl16(gs + i * 512, ld + i * 1024);
    }

    // ---- GEMM1(t): S^T(32q x 16p), 3-term split, 6 independent chains ----
    const ushort* Qhi = (const ushort*)cur;
    const ushort* Qlo = (const ushort*)(cur + 16384);
    floatx4 s0hh = (floatx4){0.f, 0.f, 0.f, 0.f};
    floatx4 s0hl = (floatx4){0.f, 0.f, 0.f, 0.f};
    floatx4 s0lh = (floatx4){0.f, 0.f, 0.f, 0.f};
    floatx4 s1hh = (floatx4){0.f, 0.f, 0.f, 0.f};
    floatx4 s1hl = (floatx4){0.f, 0.f, 0.f, 0.f};
    floatx4 s1lh = (floatx4){0.f, 0.f, 0.f, 0.f};
#pragma unroll
    for (int c = 0; c < 8; ++c) {
      short8 a0h = *(const short8*)&Qhi[goff[c]];
      short8 a0l = *(const short8*)&Qlo[goff[c]];
      short8 a1h = *(const short8*)&Qhi[goff[c] + 4096];
      short8 a1l = *(const short8*)&Qlo[goff[c] + 4096];
      s0hh = __builtin_amdgcn_mfma_f32_16x16x32_bf16(a0h, bhi[c], s0hh, 0, 0, 0);
      s0hl = __builtin_amdgcn_mfma_f32_16x16x32_bf16(a0h, blo[c], s0hl, 0, 0, 0);
      s0lh = __builtin_amdgcn_mfma_f32_16x16x32_bf16(a0l, bhi[c], s0lh, 0, 0, 0);
      s1hh = __builtin_amdgcn_mfma_f32_16x16x32_bf16(a1h, bhi[c], s1hh, 0, 0, 0);
      s1hl = __builtin_amdgcn_mfma_f32_16x16x32_bf16(a1h, blo[c], s1hl, 0, 0, 0);
      s1lh = __builtin_amdgcn_mfma_f32_16x16x32_bf16(a1l, bhi[c], s1lh, 0, 0, 0);
    }
    floatx4 s0 = (s0hh + s0hl) + s0lh;
    floatx4 s1 = (s1hh + s1hl) + s1lh;

    // ---- GEMM2(t-1): O += P(t-1)*Vhi(t-1), 2-term (phi,plo in regs) ----
    if (t > 0) {
      const ushort* TQ = (const ushort*)(prv + 32768);
#pragma unroll
      for (int nt = 0; nt < 16; ++nt) {
        short8 vhi = *(const short8*)&TQ[nt * 512 + vtoff];
        accO[nt] = __builtin_amdgcn_mfma_f32_16x16x32_bf16(phi, vhi, accO[nt], 0, 0, 0);
        accO[nt] = __builtin_amdgcn_mfma_f32_16x16x32_bf16(plo, vhi, accO[nt], 0, 0, 0);
      }
    }

    // ---- softmax(t): fixed shift, deferred reductions ----
    float pv[8];
#pragma unroll
    for (int r = 0; r < 4; ++r) {
      float s = s0[r];
      mx = fmaxf(mx, s);
      pv[r] = __expf(s - 60.f);
      ps += pv[r];
    }
#pragma unroll
    for (int r = 0; r < 4; ++r) {
      float s = s1[r];
      mx = fmaxf(mx, s);
      pv[4 + r] = __expf(s - 60.f);
      ps += pv[4 + r];
    }

    // ---- Ptrans(t): via dead SQhi of prv (same-wave, private slice) ----
    unsigned* pwv = (unsigned*)prv + w * 512;
#pragma unroll
    for (int mt = 0; mt < 2; ++mt) {
      unsigned pk[4];
#pragma unroll
      for (int r = 0; r < 4; ++r) {
        float x = pv[mt * 4 + r];
        ushort h = bf16_rne(x);
        ushort lo = bf16_rne(x - bf16f(h));
        pk[r] = (unsigned)h | ((unsigned)lo << 16);
      }
      int g = l15 * 8 + ((mt * 4 + quad) ^ swz);
      *(uint4*)&pwv[g * 4] = *(uint4*)pk;
    }
    uint4 u0 = *(const uint4*)&pwv[(l15 * 8 + ((2 * quad) ^ swz)) * 4];
    uint4 u1 = *(const uint4*)&pwv[(l15 * 8 + ((2 * quad + 1) ^ swz)) * 4];
    unsigned ua[8] = {u0.x, u0.y, u0.z, u0.w, u1.x, u1.y, u1.z, u1.w};
#pragma unroll
    for (int j = 0; j < 8; ++j) {
      phi[j] = (short)(ua[j] & 0xffffu);
      plo[j] = (short)(ua[j] >> 16);
    }
    __syncthreads();  // drain own DMA(t+1); phase boundary
  }

  // ---- GEMM2(31): tile 31 lives in buf[31%3 = 1] ----
  {
    const ushort* TQ = (const ushort*)(sm + 49152 + 32768);
#pragma unroll
    for (int nt = 0; nt < 16; ++nt) {
      short8 vhi = *(const short8*)&TQ[nt * 512 + vtoff];
      accO[nt] = __builtin_amdgcn_mfma_f32_16x16x32_bf16(phi, vhi, accO[nt], 0, 0, 0);
      accO[nt] = __builtin_amdgcn_mfma_f32_16x16x32_bf16(plo, vhi, accO[nt], 0, 0, 0);
    }
  }

  // ---- final reductions (once) ----
  ps += __shfl_xor(ps, 16);
  ps += __shfl_xor(ps, 32);
  mx = fmaxf(mx, __shfl_xor(mx, 16));
  mx = fmaxf(mx, __shfl_xor(mx, 32));

  // ---- epilogue ----
  __syncthreads();  // all waves done with buffers before Of scratch reuse
  float* Of = (float*)(sm + w * 16640);  // 16 x 260 fp32 per wave
#pragma unroll
  for (int nt = 0; nt < 16; ++nt)
#pragma unroll
    for (int r = 0; r < 4; ++r)
      Of[(quad * 4 + r) * 260 + nt * 16 + l15] = accO[nt][r];
  const float4 w1 = *(const float4*)(w_attn + lane * 4);
  const size_t rowoff = (size_t)b * PP + p0 + w * 16;
  float4 qacc = make_float4(0.f, 0.f, 0.f, 0.f);
  float dacc = 0.f;
#pragma unroll
  for (int j = 0; j < 16; ++j) {
    float4 o = *(const float4*)&Of[j * 260 + lane * 4];
    float linv = 1.f / __shfl(ps, j);
    float4 pv4 = *(const float4*)(pass + (rowoff + j) * DD + lane * 4);
    // fused kB2: q2c partial with weight e^{rowmax-60}
    float wj = __expf(__shfl(mx, j) - 60.f);
    qacc.x += wj * pv4.x; qacc.y += wj * pv4.y;
    qacc.z += wj * pv4.z; qacc.w += wj * pv4.w;
    dacc += wj;
    float tpx = ftanh(pv4.x), tpy = ftanh(pv4.y), tpz = ftanh(pv4.z), tpw = ftanh(pv4.w);
    float4 f;
    f.x = tpx * ftanh(o.x * linv);
    f.y = tpy * ftanh(o.y * linv);
    f.z = tpz * ftanh(o.z * linv);
    f.w = tpw * ftanh(o.w * linv);
    half4 fh = {(_Float16)f.x, (_Float16)f.y, (_Float16)f.z, (_Float16)f.w};
    half4 th = {(_Float16)tpx, (_Float16)tpy, (_Float16)tpz, (_Float16)tpw};
    *(half4*)(first_h + (rowoff + j) * DD + lane * 4) = fh;
    *(half4*)(tp_h + (rowoff + j) * DD + lane * 4) = th;
    float part = f.x * w1.x + f.y * w1.y + f.z * w1.z + f.w * w1.w;
    part += __shfl_xor(part, 1);  part += __shfl_xor(part, 2);
    part += __shfl_xor(part, 4);  part += __shfl_xor(part, 8);
    part += __shfl_xor(part, 16); part += __shfl_xor(part, 32);
    if (lane == 0) logit1[rowoff + j] = part;
  }

  // ---- fused kB2 reduction: 8 per-wave partials -> numpart/denpart ----
  float* redw = (float*)(sm + w * 16640);  // own Of slice, reads all done
  *(float4*)&redw[lane * 4] = qacc;
  if (lane == 0) redw[256] = dacc;
  __syncthreads();
  if (w == 0) {
    float4 s = make_float4(0.f, 0.f, 0.f, 0.f);
    float dsum = 0.f;
#pragma unroll
    for (int wv = 0; wv < 8; ++wv) {
      const float* rp = (const float*)(sm + wv * 16640);
      float4 v = *(const float4*)&rp[lane * 4];
      s.x += v.x; s.y += v.y; s.z += v.z; s.w += v.w;
      dsum += rp[256];
    }
    *(float4*)(numpart + (size_t)(blockIdx.x * 16 + b) * DD + lane * 4) = s;
    if (lane == 0) denpart[blockIdx.x * 16 + b] = dsum;
  }
}

// ---------------------------------------------------------------------------
// kE: fused kB3 + kC + reducer partials.  64 chunks x 64 p (4 blocks/CU).
// Per block: recompute w2tq from numpart/denpart (kB3's op order), then per
// row p: logit-dot from tp_h (kC's op order), wgt = exp(logit1 + dot);
// accumulate weighted f/t partials.
// ---------------------------------------------------------------------------
__global__ __launch_bounds__(256) void kE(
    const _Float16* __restrict__ tp_h, const _Float16* __restrict__ first_h,
    const float* __restrict__ logit1,
    const float* __restrict__ numpart, const float* __restrict__ denpart,
    const float* __restrict__ w_attn,
    float* __restrict__ r1part, float* __restrict__ r2part, float* __restrict__ den2part)
{
  const int b = blockIdx.y, chunk = blockIdx.x;   // 64 chunks x 64 p
  const int tid = threadIdx.x, r = tid >> 6, ln = tid & 63;
  __shared__ float s1[4][64][4];
  __shared__ float s2[4][64][4];
  __shared__ float sd[4][64];
  __shared__ alignas(16) float w2s[256];
  // fused kB3: w2tq[d] = w_attn[D+d] * tanh(sum num / sum den)
  {
    float num = 0.f, den = 0.f;
#pragma unroll
    for (int c = 0; c < 32; ++c) {
      num += numpart[(size_t)(c * 16 + b) * DD + tid];
      den += denpart[c * 16 + b];
    }
    w2s[tid] = w_attn[DD + tid] * ftanh(num / den);
  }
  __syncthreads();
  const float4 wv = *(const float4*)&w2s[ln << 2];
  const float* lg = logit1 + (size_t)b * PP + chunk * 64;
  const size_t base = ((size_t)b * PP + chunk * 64) * DD;
  float a1[4] = {0.f, 0.f, 0.f, 0.f}, a2[4] = {0.f, 0.f, 0.f, 0.f};
  float den = 0.f;
  for (int p = r; p < 64; p += 4) {
    half4 f = *(const half4*)(first_h + base + (size_t)p * DD + ln * 4);
    half4 t = *(const half4*)(tp_h + base + (size_t)p * DD + ln * 4);
    float part = (float)t.x * wv.x + (float)t.y * wv.y +
                 (float)t.z * wv.z + (float)t.w * wv.w;
    part += __shfl_xor(part, 1);  part += __shfl_xor(part, 2);
    part += __shfl_xor(part, 4);  part += __shfl_xor(part, 8);
    part += __shfl_xor(part, 16); part += __shfl_xor(part, 32);
    float wgt = __expf(lg[p] + part);
    a1[0] += wgt * (float)f.x; a1[1] += wgt * (float)f.y;
    a1[2] += wgt * (float)f.z; a1[3] += wgt * (float)f.w;
    a2[0] += wgt * (float)t.x; a2[1] += wgt * (float)t.y;
    a2[2] += wgt * (float)t.z; a2[3] += wgt * (float)t.w;
    den += wgt;
  }
  *(float4*)&s1[r][ln][0] = *(float4*)a1;
  *(float4*)&s2[r][ln][0] = *(float4*)a2;
  sd[r][ln] = den;
  __syncthreads();
  if (r == 0) {
    float o1[4], o2[4];
#pragma unroll
    for (int i = 0; i < 4; ++i) {
      o1[i] = s1[0][ln][i] + s1[1][ln][i] + s1[2][ln][i] + s1[3][ln][i];
      o2[i] = s2[0][ln][i] + s2[1][ln][i] + s2[2][ln][i] + s2[3][ln][i];
    }
    *(float4*)(r1part + (size_t)(chunk * 16 + b) * DD + ln * 4) = *(float4*)o1;
    *(float4*)(r2part + (size_t)(chunk * 16 + b) * DD + ln * 4) = *(float4*)o2;
    if (ln == 0)
      den2part[chunk * 16 + b] = sd[0][0] + sd[1][0] + sd[2][0] + sd[3][0];
  }
}

// ---------------------------------------------------------------------------
// kF: 64 blocks = (16 b x 4 o-groups).  Phase A: build R1/R2 in LDS
// (64-chunk reduction + tq recompute).  Phase B: 4-way k-split dot + reduce.
// ---------------------------------------------------------------------------
__global__ __launch_bounds__(256) void kF(
    const float* __restrict__ r1part, const float* __restrict__ r2part,
    const float* __restrict__ den2part,
    const float* __restrict__ numpart, const float* __restrict__ denpart,
    const float* __restrict__ w_out, const float* __restrict__ b_out,
    float* __restrict__ out)
{
  const int b = blockIdx.x >> 2, og = blockIdx.x & 3;
  const int tid = threadIdx.x;
  __shared__ alignas(16) float R1[256], R2[256];
  __shared__ float sacc[4][64];
  {
    float red1 = 0.f, red2 = 0.f, den2 = 0.f;
#pragma unroll
    for (int c = 0; c < 64; ++c) {
      red1 += r1part[(size_t)(c * 16 + b) * DD + tid];
      red2 += r2part[(size_t)(c * 16 + b) * DD + tid];
      den2 += den2part[c * 16 + b];
    }
    float num = 0.f, den = 0.f;
#pragma unroll
    for (int c = 0; c < 32; ++c) {
      num += numpart[(size_t)(c * 16 + b) * DD + tid];
      den += denpart[c * 16 + b];
    }
    float t = ftanh(num / den);
    float inv = 1.f / den2;
    R1[tid] = red1 * inv;
    R2[tid] = red2 * inv * t;
  }
  __syncthreads();
  const int oi = tid & 63, ks = tid >> 6;
  const int o = og * 64 + oi;
  float acc = 0.f;
  for (int k = ks * 64; k < ks * 64 + 64; ++k) {
    acc += R1[k] * w_out[k * 256 + o];
    acc += R2[k] * w_out[(DD + k) * 256 + o];
  }
  sacc[ks][oi] = acc;
  __syncthreads();
  if (ks == 0) {
    float v = sacc[0][oi] + sacc[1][oi] + sacc[2][oi] + sacc[3][oi];
    out[b * 256 + o] = v + b_out[o];
  }
}

extern "C" void kernel_launch(void* const* d_in, const int* in_sizes, int n_in,
                              void* d_out, int out_size, void* d_ws, size_t ws_size,
                              hipStream_t stream) {
  const float* pass   = (const float*)d_in[0];
  const float* ques   = (const float*)d_in[1];
  const float* w_attn = (const float*)d_in[2];
  // d_in[3] = b_attn: uniform softmax shift, cancels in num/den -> dropped
  const float* w_out  = (const float*)d_in[4];
  const float* b_out  = (const float*)d_in[5];
  float* out = (float*)d_out;

  float* ws       = (float*)d_ws;
  float* logit1   = ws;                                   // BB*PP
  float* numpart  = logit1   + (size_t)BB * PP;           // 32*BB*DD
  float* denpart  = numpart  + (size_t)32 * BB * DD;      // 32*BB
  float* r1part   = denpart  + 32 * BB;                   // 64*BB*DD
  float* r2part   = r1part   + (size_t)64 * BB * DD;      // 64*BB*DD
  float* den2part = r2part   + (size_t)64 * BB * DD;      // 64*BB
  ushort* qbb     = (ushort*)(den2part + 64 * BB);        // BB*32*24576 ushorts
  _Float16* first_h = (_Float16*)(qbb + (size_t)BB * 32 * 24576);
  _Float16* tp_h    = first_h + (size_t)BB * PP * DD;

  kQprep<<<dim3(QQ / 32, BB), 256, 0, stream>>>(ques, qbb);
  kA    <<<dim3(PP / 128, BB), 512, 0, stream>>>(pass, qbb, w_attn,
                                                 first_h, tp_h, logit1,
                                                 numpart, denpart);
  kE    <<<dim3(64, BB), 256, 0, stream>>>(tp_h, first_h, logit1,
                                           numpart, denpart, w_attn,
                                           r1part, r2part, den2part);
  kF    <<<64, 256, 0, stream>>>(r1part, r2part, den2part,
                                 numpart, denpart, w_out, b_out, out);
}

// Round 7
// 320.873 us; speedup vs baseline: 1.0363x; 1.0363x over previous
//
#include <hip/hip_runtime.h>
#include <cmath>

#define BB 16
#define PP 4096
#define QQ 1024
#define DD 256

typedef __attribute__((ext_vector_type(8))) short short8;
typedef __attribute__((ext_vector_type(4))) float floatx4;
typedef __attribute__((ext_vector_type(4))) _Float16 half4;

static __device__ inline ushort bf16_rne(float x) {
  unsigned u = __float_as_uint(x);
  unsigned r = (u + 0x7fffu + ((u >> 16) & 1u)) >> 16;
  return (ushort)r;
}
static __device__ inline float bf16f(ushort h) { return __uint_as_float(((unsigned)h) << 16); }

static __device__ inline float ftanh(float x) {
  float e = __expf(2.0f * x);
  return 1.0f - 2.0f * __builtin_amdgcn_rcpf(e + 1.0f);
}

static __device__ inline void gl16(const void* g, void* l) {
  __builtin_amdgcn_global_load_lds(
      (const __attribute__((address_space(1))) unsigned int*)g,
      (__attribute__((address_space(3))) unsigned int*)l, 16, 0, 0);
}

// ---------------------------------------------------------------------------
// kQprep: Q -> per-(b,32q-tile) 48KB blobs: [SQhi 16K | SQlo 16K | TQhi 16K].
//  SQ: row-major hi/lo, granule j of row r at slot j^(r&7).
//  TQ: transposed [d][32q] bf16-hi, granule k at slot k^((d>>1)&3).
//  TQ granule CONTENT is k-permuted for direct-register GEMM2 A-frags in kA:
//  granule k = [q=k*4+0..3 | q=16+k*4+0..3]  (k-index q(quad,j)=(j>>2)*16+quad*4+(j&3))
// ---------------------------------------------------------------------------
__global__ __launch_bounds__(256) void kQprep(
    const float* __restrict__ ques, ushort* __restrict__ qb)
{
  const int b = blockIdx.y, qt = blockIdx.x;
  __shared__ float tile[32][260];
  const int tid = threadIdx.x;
  const float* src = ques + ((size_t)b * QQ + qt * 32) * DD;
  for (int i = tid; i < 32 * 64; i += 256) {
    int r = i >> 6, c = (i & 63) << 2;
    *(float4*)&tile[r][c] = *(const float4*)(src + r * DD + c);
  }
  __syncthreads();
  ushort* blob = qb + (size_t)(b * 32 + qt) * 24576;
  {
    int r = tid >> 3;
    int j0 = (tid & 7) * 4;
#pragma unroll
    for (int jj = 0; jj < 4; ++jj) {
      int j = j0 + jj;
      ushort h8[8], l8[8];
#pragma unroll
      for (int e = 0; e < 8; ++e) {
        float x = tile[r][j * 8 + e];
        ushort h = bf16_rne(x);
        h8[e] = h; l8[e] = bf16_rne(x - bf16f(h));
      }
      int g = r * 32 + (j ^ (r & 7));
      *(uint4*)&blob[(size_t)g * 8] = *(uint4*)h8;
      *(uint4*)&blob[8192 + (size_t)g * 8] = *(uint4*)l8;
    }
  }
  {
    int d = tid;
    int s = (d >> 1) & 3;
    ushort h32[32];
#pragma unroll
    for (int r = 0; r < 32; ++r) h32[r] = bf16_rne(tile[r][d]);
#pragma unroll
    for (int k = 0; k < 4; ++k) {
      ushort g8[8];
#pragma unroll
      for (int e = 0; e < 4; ++e) {
        g8[e]     = h32[k * 4 + e];        // half 0: q = k*4+e
        g8[4 + e] = h32[16 + k * 4 + e];   // half 1: q = 16+k*4+e
      }
      *(uint4*)&blob[16384 + (size_t)d * 32 + (k ^ s) * 8] = *(uint4*)g8;
    }
  }
}

// ---------------------------------------------------------------------------
// kA: flash attention, cross-iteration pipelined (round-0 structure).
// 512 thr = 8 waves x 16 p-rows; triple-buffered 48KB Q tiles (1 block/CU).
// iter t: DMA(t+1) | GEMM1(t) | GEMM2(t-1) (P in regs) | softmax(t)+pack.
// NO Ptrans: GEMM2's k-dim uses the permuted q-order q(quad,j) =
// (j>>2)*16 + quad*4 + (j&3), under which each lane's own s0[r]/s1[r] ARE its
// A-fragment entries; TQ granules carry V in matching k-order (see kQprep).
// Fixed-shift softmax (C=60), l/rowmax reductions deferred to the end.
// Epilogue FUSES kB2: per-block q2c partials (weight e^{rowmax-60}).
// ---------------------------------------------------------------------------
__global__ __launch_bounds__(512, 1) void kA(
    const float* __restrict__ pass, const ushort* __restrict__ qb,
    const float* __restrict__ w_attn,
    _Float16* __restrict__ first_h, _Float16* __restrict__ tp_h,
    float* __restrict__ logit1,
    float* __restrict__ numpart, float* __restrict__ denpart)
{
  __shared__ alignas(16) char sm[147456];  // 3 x 48KB buffers

  const int b    = blockIdx.y;
  const int p0   = blockIdx.x * 128;
  const int tid  = threadIdx.x;
  const int w    = tid >> 6;
  const int lane = tid & 63;
  const int l15  = lane & 15;
  const int quad = lane >> 4;
  const int swz  = l15 & 7;

  // passage B-fragments (hi/lo), once per block
  short8 bhi[8], blo[8];
  {
    const float* prow = pass + (((size_t)b * PP + p0 + w * 16 + l15) * DD);
#pragma unroll
    for (int c = 0; c < 8; ++c) {
      const float* p8 = prow + c * 32 + quad * 8;
      float4 x0 = *(const float4*)p8;
      float4 x1 = *(const float4*)(p8 + 4);
      float xs[8] = {x0.x, x0.y, x0.z, x0.w, x1.x, x1.y, x1.z, x1.w};
#pragma unroll
      for (int j = 0; j < 8; ++j) {
        ushort h = bf16_rne(xs[j]);
        ushort lo = bf16_rne(xs[j] - bf16f(h));
        bhi[c][j] = (short)h;
        blo[c][j] = (short)lo;
      }
    }
  }

  int goff[8];
#pragma unroll
  for (int c = 0; c < 8; ++c) goff[c] = (l15 * 32 + ((4 * c + quad) ^ swz)) * 8;
  const int vtoff = l15 * 32 + ((quad ^ ((l15 >> 1) & 3)) * 8);

  const ushort* tb = qb + (size_t)b * 32 * 24576;
  const int dma_l = w * 3072 + lane * 8;   // ushort offset in blob
  const int dma_s = w * 6144 + lane * 16;  // byte offset in LDS buffer

  floatx4 accO[16];
#pragma unroll
  for (int i = 0; i < 16; ++i) accO[i] = (floatx4){0.f, 0.f, 0.f, 0.f};
  float mx = -INFINITY, ps = 0.f;
  short8 phi = {0, 0, 0, 0, 0, 0, 0, 0}, plo = {0, 0, 0, 0, 0, 0, 0, 0};

  // DMA(0) -> buf0
  {
    const ushort* gs = tb + dma_l;
    char* ld = sm + dma_s;
#pragma unroll
    for (int i = 0; i < 6; ++i) gl16(gs + i * 512, ld + i * 1024);
  }
  __syncthreads();

  for (int t = 0; t < 32; ++t) {
    const int ic = t % 3, ip = (t + 2) % 3, inx = (t + 1) % 3;
    char* cur = sm + ic * 49152;
    char* prv = sm + ip * 49152;
    if (t < 31) {
      const ushort* gs = tb + (size_t)(t + 1) * 24576 + dma_l;
      char* ld = sm + inx * 49152 + dma_s;
#pragma unroll
      for (int i = 0; i < 6; ++i) gl16(gs + i * 512, ld + i * 1024);
    }

    // ---- GEMM1(t): S^T(32q x 16p), 3-term split ----
    const ushort* Qhi = (const ushort*)cur;
    const ushort* Qlo = (const ushort*)(cur + 16384);
    floatx4 s0 = (floatx4){0.f, 0.f, 0.f, 0.f};
    floatx4 s1 = (floatx4){0.f, 0.f, 0.f, 0.f};
#pragma unroll
    for (int c = 0; c < 8; ++c) {
      short8 a0h = *(const short8*)&Qhi[goff[c]];
      short8 a0l = *(const short8*)&Qlo[goff[c]];
      short8 a1h = *(const short8*)&Qhi[goff[c] + 4096];
      short8 a1l = *(const short8*)&Qlo[goff[c] + 4096];
      s0 = __builtin_amdgcn_mfma_f32_16x16x32_bf16(a0h, bhi[c], s0, 0, 0, 0);
      s0 = __builtin_amdgcn_mfma_f32_16x16x32_bf16(a0h, blo[c], s0, 0, 0, 0);
      s0 = __builtin_amdgcn_mfma_f32_16x16x32_bf16(a0l, bhi[c], s0, 0, 0, 0);
      s1 = __builtin_amdgcn_mfma_f32_16x16x32_bf16(a1h, bhi[c], s1, 0, 0, 0);
      s1 = __builtin_amdgcn_mfma_f32_16x16x32_bf16(a1h, blo[c], s1, 0, 0, 0);
      s1 = __builtin_amdgcn_mfma_f32_16x16x32_bf16(a1l, bhi[c], s1, 0, 0, 0);
    }

    // ---- GEMM2(t-1): O += P(t-1)*Vhi(t-1), 2-term (phi,plo in regs) ----
    if (t > 0) {
      const ushort* TQ = (const ushort*)(prv + 32768);
#pragma unroll
      for (int nt = 0; nt < 16; ++nt) {
        short8 vhi = *(const short8*)&TQ[nt * 512 + vtoff];
        accO[nt] = __builtin_amdgcn_mfma_f32_16x16x32_bf16(phi, vhi, accO[nt], 0, 0, 0);
        accO[nt] = __builtin_amdgcn_mfma_f32_16x16x32_bf16(plo, vhi, accO[nt], 0, 0, 0);
      }
    }

    // ---- softmax(t): fixed shift, deferred reductions; pack P directly ----
    // lane (l15,quad) holds S[q=quad*4+r][p=l15] (s0) and S[16+quad*4+r][p=l15]
    // (s1) — exactly A-frag entries k=quad*8+r and k=quad*8+4+r in the
    // permuted k-order. No LDS transpose needed.
    {
      short8 nph, npl;
#pragma unroll
      for (int r = 0; r < 4; ++r) {
        float s = s0[r];
        mx = fmaxf(mx, s);
        float x = __expf(s - 60.f);
        ps += x;
        ushort h = bf16_rne(x);
        nph[r] = (short)h;
        npl[r] = (short)bf16_rne(x - bf16f(h));
      }
#pragma unroll
      for (int r = 0; r < 4; ++r) {
        float s = s1[r];
        mx = fmaxf(mx, s);
        float x = __expf(s - 60.f);
        ps += x;
        ushort h = bf16_rne(x);
        nph[4 + r] = (short)h;
        npl[4 + r] = (short)bf16_rne(x - bf16f(h));
      }
      phi = nph;
      plo = npl;
    }
    __syncthreads();  // drain own DMA(t+1); phase boundary
  }

  // ---- GEMM2(31): tile 31 lives in buf[31%3 = 1] ----
  {
    const ushort* TQ = (const ushort*)(sm + 49152 + 32768);
#pragma unroll
    for (int nt = 0; nt < 16; ++nt) {
      short8 vhi = *(const short8*)&TQ[nt * 512 + vtoff];
      accO[nt] = __builtin_amdgcn_mfma_f32_16x16x32_bf16(phi, vhi, accO[nt], 0, 0, 0);
      accO[nt] = __builtin_amdgcn_mfma_f32_16x16x32_bf16(plo, vhi, accO[nt], 0, 0, 0);
    }
  }

  // ---- final reductions (once) ----
  ps += __shfl_xor(ps, 16);
  ps += __shfl_xor(ps, 32);
  mx = fmaxf(mx, __shfl_xor(mx, 16));
  mx = fmaxf(mx, __shfl_xor(mx, 32));

  // ---- epilogue ----
  __syncthreads();  // all waves done with buffers before Of scratch reuse
  float* Of = (float*)(sm + w * 16640);  // 16 x 260 fp32 per wave
#pragma unroll
  for (int nt = 0; nt < 16; ++nt)
#pragma unroll
    for (int r = 0; r < 4; ++r)
      Of[(quad * 4 + r) * 260 + nt * 16 + l15] = accO[nt][r];
  const float4 w1 = *(const float4*)(w_attn + lane * 4);
  const size_t rowoff = (size_t)b * PP + p0 + w * 16;
  float4 qacc = make_float4(0.f, 0.f, 0.f, 0.f);
  float dacc = 0.f;
#pragma unroll
  for (int j = 0; j < 16; ++j) {
    float4 o = *(const float4*)&Of[j * 260 + lane * 4];
    float linv = 1.f / __shfl(ps, j);
    float4 pv4 = *(const float4*)(pass + (rowoff + j) * DD + lane * 4);
    // fused kB2: q2c partial with weight e^{rowmax-60}
    float wj = __expf(__shfl(mx, j) - 60.f);
    qacc.x += wj * pv4.x; qacc.y += wj * pv4.y;
    qacc.z += wj * pv4.z; qacc.w += wj * pv4.w;
    dacc += wj;
    float tpx = ftanh(pv4.x), tpy = ftanh(pv4.y), tpz = ftanh(pv4.z), tpw = ftanh(pv4.w);
    float4 f;
    f.x = tpx * ftanh(o.x * linv);
    f.y = tpy * ftanh(o.y * linv);
    f.z = tpz * ftanh(o.z * linv);
    f.w = tpw * ftanh(o.w * linv);
    half4 fh = {(_Float16)f.x, (_Float16)f.y, (_Float16)f.z, (_Float16)f.w};
    half4 th = {(_Float16)tpx, (_Float16)tpy, (_Float16)tpz, (_Float16)tpw};
    *(half4*)(first_h + (rowoff + j) * DD + lane * 4) = fh;
    *(half4*)(tp_h + (rowoff + j) * DD + lane * 4) = th;
    float part = f.x * w1.x + f.y * w1.y + f.z * w1.z + f.w * w1.w;
    part += __shfl_xor(part, 1);  part += __shfl_xor(part, 2);
    part += __shfl_xor(part, 4);  part += __shfl_xor(part, 8);
    part += __shfl_xor(part, 16); part += __shfl_xor(part, 32);
    if (lane == 0) logit1[rowoff + j] = part;
  }

  // ---- fused kB2 reduction: 8 per-wave partials -> numpart/denpart ----
  float* redw = (float*)(sm + w * 16640);  // own Of slice, reads all done
  *(float4*)&redw[lane * 4] = qacc;
  if (lane == 0) redw[256] = dacc;
  __syncthreads();
  if (w == 0) {
    float4 s = make_float4(0.f, 0.f, 0.f, 0.f);
    float dsum = 0.f;
#pragma unroll
    for (int wv = 0; wv < 8; ++wv) {
      const float* rp = (const float*)(sm + wv * 16640);
      float4 v = *(const float4*)&rp[lane * 4];
      s.x += v.x; s.y += v.y; s.z += v.z; s.w += v.w;
      dsum += rp[256];
    }
    *(float4*)(numpart + (size_t)(blockIdx.x * 16 + b) * DD + lane * 4) = s;
    if (lane == 0) denpart[blockIdx.x * 16 + b] = dsum;
  }
}

// ---------------------------------------------------------------------------
// kE: fused kB3 + kC + reducer partials.  64 chunks x 64 p (4 blocks/CU).
// Per block: recompute w2tq from numpart/denpart (kB3's op order), then per
// row p: logit-dot from tp_h (kC's op order), wgt = exp(logit1 + dot);
// accumulate weighted f/t partials.
// ---------------------------------------------------------------------------
__global__ __launch_bounds__(256) void kE(
    const _Float16* __restrict__ tp_h, const _Float16* __restrict__ first_h,
    const float* __restrict__ logit1,
    const float* __restrict__ numpart, const float* __restrict__ denpart,
    const float* __restrict__ w_attn,
    float* __restrict__ r1part, float* __restrict__ r2part, float* __restrict__ den2part)
{
  const int b = blockIdx.y, chunk = blockIdx.x;   // 64 chunks x 64 p
  const int tid = threadIdx.x, r = tid >> 6, ln = tid & 63;
  __shared__ float s1[4][64][4];
  __shared__ float s2[4][64][4];
  __shared__ float sd[4][64];
  __shared__ alignas(16) float w2s[256];
  // fused kB3: w2tq[d] = w_attn[D+d] * tanh(sum num / sum den)
  {
    float num = 0.f, den = 0.f;
#pragma unroll
    for (int c = 0; c < 32; ++c) {
      num += numpart[(size_t)(c * 16 + b) * DD + tid];
      den += denpart[c * 16 + b];
    }
    w2s[tid] = w_attn[DD + tid] * ftanh(num / den);
  }
  __syncthreads();
  const float4 wv = *(const float4*)&w2s[ln << 2];
  const float* lg = logit1 + (size_t)b * PP + chunk * 64;
  const size_t base = ((size_t)b * PP + chunk * 64) * DD;
  float a1[4] = {0.f, 0.f, 0.f, 0.f}, a2[4] = {0.f, 0.f, 0.f, 0.f};
  float den = 0.f;
  for (int p = r; p < 64; p += 4) {
    half4 f = *(const half4*)(first_h + base + (size_t)p * DD + ln * 4);
    half4 t = *(const half4*)(tp_h + base + (size_t)p * DD + ln * 4);
    float part = (float)t.x * wv.x + (float)t.y * wv.y +
                 (float)t.z * wv.z + (float)t.w * wv.w;
    part += __shfl_xor(part, 1);  part += __shfl_xor(part, 2);
    part += __shfl_xor(part, 4);  part += __shfl_xor(part, 8);
    part += __shfl_xor(part, 16); part += __shfl_xor(part, 32);
    float wgt = __expf(lg[p] + part);
    a1[0] += wgt * (float)f.x; a1[1] += wgt * (float)f.y;
    a1[2] += wgt * (float)f.z; a1[3] += wgt * (float)f.w;
    a2[0] += wgt * (float)t.x; a2[1] += wgt * (float)t.y;
    a2[2] += wgt * (float)t.z; a2[3] += wgt * (float)t.w;
    den += wgt;
  }
  *(float4*)&s1[r][ln][0] = *(float4*)a1;
  *(float4*)&s2[r][ln][0] = *(float4*)a2;
  sd[r][ln] = den;
  __syncthreads();
  if (r == 0) {
    float o1[4], o2[4];
#pragma unroll
    for (int i = 0; i < 4; ++i) {
      o1[i] = s1[0][ln][i] + s1[1][ln][i] + s1[2][ln][i] + s1[3][ln][i];
      o2[i] = s2[0][ln][i] + s2[1][ln][i] + s2[2][ln][i] + s2[3][ln][i];
    }
    *(float4*)(r1part + (size_t)(chunk * 16 + b) * DD + ln * 4) = *(float4*)o1;
    *(float4*)(r2part + (size_t)(chunk * 16 + b) * DD + ln * 4) = *(float4*)o2;
    if (ln == 0)
      den2part[chunk * 16 + b] = sd[0][0] + sd[1][0] + sd[2][0] + sd[3][0];
  }
}

// ---------------------------------------------------------------------------
// kF: 64 blocks = (16 b x 4 o-groups).  Phase A: build R1/R2 in LDS
// (64-chunk reduction + tq recompute).  Phase B: 4-way k-split dot + reduce.
// ---------------------------------------------------------------------------
__global__ __launch_bounds__(256) void kF(
    const float* __restrict__ r1part, const float* __restrict__ r2part,
    const float* __restrict__ den2part,
    const float* __restrict__ numpart, const float* __restrict__ denpart,
    const float* __restrict__ w_out, const float* __restrict__ b_out,
    float* __restrict__ out)
{
  const int b = blockIdx.x >> 2, og = blockIdx.x & 3;
  const int tid = threadIdx.x;
  __shared__ alignas(16) float R1[256], R2[256];
  __shared__ float sacc[4][64];
  {
    float red1 = 0.f, red2 = 0.f, den2 = 0.f;
#pragma unroll
    for (int c = 0; c < 64; ++c) {
      red1 += r1part[(size_t)(c * 16 + b) * DD + tid];
      red2 += r2part[(size_t)(c * 16 + b) * DD + tid];
      den2 += den2part[c * 16 + b];
    }
    float num = 0.f, den = 0.f;
#pragma unroll
    for (int c = 0; c < 32; ++c) {
      num += numpart[(size_t)(c * 16 + b) * DD + tid];
      den += denpart[c * 16 + b];
    }
    float t = ftanh(num / den);
    float inv = 1.f / den2;
    R1[tid] = red1 * inv;
    R2[tid] = red2 * inv * t;
  }
  __syncthreads();
  const int oi = tid & 63, ks = tid >> 6;
  const int o = og * 64 + oi;
  float acc = 0.f;
  for (int k = ks * 64; k < ks * 64 + 64; ++k) {
    acc += R1[k] * w_out[k * 256 + o];
    acc += R2[k] * w_out[(DD + k) * 256 + o];
  }
  sacc[ks][oi] = acc;
  __syncthreads();
  if (ks == 0) {
    float v = sacc[0][oi] + sacc[1][oi] + sacc[2][oi] + sacc[3][oi];
    out[b * 256 + o] = v + b_out[o];
  }
}

extern "C" void kernel_launch(void* const* d_in, const int* in_sizes, int n_in,
                              void* d_out, int out_size, void* d_ws, size_t ws_size,
                              hipStream_t stream) {
  const float* pass   = (const float*)d_in[0];
  const float* ques   = (const float*)d_in[1];
  const float* w_attn = (const float*)d_in[2];
  // d_in[3] = b_attn: uniform softmax shift, cancels in num/den -> dropped
  const float* w_out  = (const float*)d_in[4];
  const float* b_out  = (const float*)d_in[5];
  float* out = (float*)d_out;

  float* ws       = (float*)d_ws;
  float* logit1   = ws;                                   // BB*PP
  float* numpart  = logit1   + (size_t)BB * PP;           // 32*BB*DD
  float* denpart  = numpart  + (size_t)32 * BB * DD;      // 32*BB
  float* r1part   = denpart  + 32 * BB;                   // 64*BB*DD
  float* r2part   = r1part   + (size_t)64 * BB * DD;      // 64*BB*DD
  float* den2part = r2part   + (size_t)64 * BB * DD;      // 64*BB
  ushort* qbb     = (ushort*)(den2part + 64 * BB);        // BB*32*24576 ushorts
  _Float16* first_h = (_Float16*)(qbb + (size_t)BB * 32 * 24576);
  _Float16* tp_h    = first_h + (size_t)BB * PP * DD;

  kQprep<<<dim3(QQ / 32, BB), 256, 0, stream>>>(ques, qbb);
  kA    <<<dim3(PP / 128, BB), 512, 0, stream>>>(pass, qbb, w_attn,
                                                 first_h, tp_h, logit1,
                                                 numpart, denpart);
  kE    <<<dim3(64, BB), 256, 0, stream>>>(tp_h, first_h, logit1,
                                           numpart, denpart, w_attn,
                                           r1part, r2part, den2part);
  kF    <<<64, 256, 0, stream>>>(r1part, r2part, den2part,
                                 numpart, denpart, w_out, b_out, out);
}